// Round 6
// baseline (208.752 us; speedup 1.0000x reference)
//
#include <hip/hip_runtime.h>

// RandomShiftsAug: out[n,c,h,w] = x[n,c, clamp(h+sy,0,83), clamp(w+sx,0,83)],
// sx,sy = shift[n] - 4 in [-4,4], uniform per image. Pure edge-clamped gather.
//
// R8 -> R9: persistent streaming loop (the copy-kernel's STRUCTURE, not just
// its instructions).
//   Post-mortem R8: VGPR 24->28 proves the 7-load batch WAS live (7 quads =
//   28 VGPRs) with a single forced drain -- and dur/HBM didn't move (70.7us,
//   2.44 TB/s). Deep per-thread MLP is falsified. Meanwhile the poison fill
//   sustains 6.5 TB/s at 9% occupancy / 8 VGPRs: saturation needs almost no
//   parallelism when the structure is right. What fill and m13's 6.29 TB/s
//   copy share, and ALL nine of our 59-74us variants lack: persistent
//   grid-stride loops -- long-lived waves, loop-carried prefetch, counted
//   vmcnt waits, no block churn, no full drains. Ours are launch-and-die
//   28KB blocks (16 generations/CU of ramp+drain bubbles).
//   R9: image-per-block (4 contiguous planes, 112KB in/out), grid 1024 =
//   exactly 4 blocks/CU (one generation, zero churn), 28-iter #pragma
//   unroll 1 loop with loop-carried L/Ln prefetch -- a loop-carried dep the
//   compiler cannot re-sink (unlike unrolled R6/R7); it must emit the
//   counted-vmcnt pipeline it already emits for copy loops. Addressing =
//   R8's validated clamped-base + uniform per-element select.
// Predicted: dispatch 70.7 -> ~42-50us, hbm_gbps 2430 -> ~3500-4000 (FETCH
// stays ~55MB, reads half L3-hit), VALUBusy ~20%, bench ~180us.
// Falsifier: dur >= 60us => structural space exhausted; revert to best-known
// and declare practical cap next round.

#define HW    84
#define PADV  4
#define PLANE (HW * HW)        // 7056 floats per (n,c) plane
#define QPP   (PLANE / 4)      // 1764 quads per plane
#define QPI   (4 * QPP)        // 7056 quads per image (c-planes contiguous)
#define NTHR  256
#define NIT   28               // ceil(7056/256); iter 27 is tail (tid<144)

typedef float f32x4 __attribute__((ext_vector_type(4)));
struct __attribute__((aligned(4))) f4u { float x, y, z, w; };

__device__ __forceinline__ float pick(const f4u& v, int idx) {
    return (idx < 1) ? v.x : (idx < 2) ? v.y : (idx < 3) ? v.z : v.w;
}

// source float-offset within image + select correction d for output quad G
__device__ __forceinline__ int src_addr(int G, int sx, int sy, int& d) {
    G = min(G, QPI - 1);                 // clamp tail lanes (load only)
    const int c    = G / QPP;            // magic-mul
    const int gi   = G - c * QPP;
    const int row  = gi / 21;            // magic-mul
    const int tx   = gi - row * 21;
    const int srow = min(max(row + sy, 0), HW - 1);
    const int cb   = 4 * tx + sx;        // wanted start col, may be OOB
    const int B    = min(max(cb, 0), HW - 4);
    d = cb - B;                          // in [-4,4]; 0 for interior lanes
    return c * PLANE + srow * HW + B;    // 4B-aligned quad base
}

__global__ __launch_bounds__(NTHR)
void shift_aug_kernel(const float* __restrict__ x,
                      const int* __restrict__ shift,
                      float* __restrict__ out) {
    const int tid = threadIdx.x;
    const int n   = blockIdx.x;                    // one image per block

    const int sx = shift[2 * n]     - PADV;        // uniform -> SGPR
    const int sy = shift[2 * n + 1] - PADV;

    const float* __restrict__ img  = x   + (size_t)n * (4 * PLANE);
    float*       __restrict__ oimg = out + (size_t)n * (4 * PLANE);

    // prologue: prefetch iteration 0
    int dcur;
    f4u L = *(const f4u*)(img + src_addr(tid, sx, sy, dcur));

    // steady state: prefetch j+1, consume j. Loop-carried L/Ln forces the
    // compiler to keep the prefetch ahead of the store (counted vmcnt).
    #pragma unroll 1
    for (int j = 0; j < NIT - 1; ++j) {
        int dnext;
        const f4u Ln = *(const f4u*)(img + src_addr(tid + NTHR * (j + 1), sx, sy, dnext));

        float4 o;
        o.x = pick(L, min(max(dcur,     0), 3));
        o.y = pick(L, min(max(dcur + 1, 0), 3));
        o.z = pick(L, min(max(dcur + 2, 0), 3));
        o.w = pick(L, min(max(dcur + 3, 0), 3));
        ((float4*)oimg)[tid + NTHR * j] = o;       // j<=26 -> G<=6912+? <7056, valid

        L = Ln;
        dcur = dnext;
    }

    // epilogue: iteration 27, store masked (G = tid + 6912 < 7056 <=> tid < 144)
    {
        float4 o;
        o.x = pick(L, min(max(dcur,     0), 3));
        o.y = pick(L, min(max(dcur + 1, 0), 3));
        o.z = pick(L, min(max(dcur + 2, 0), 3));
        o.w = pick(L, min(max(dcur + 3, 0), 3));
        const int G = tid + NTHR * (NIT - 1);
        if (G < QPI) ((float4*)oimg)[G] = o;
    }
}

extern "C" void kernel_launch(void* const* d_in, const int* in_sizes, int n_in,
                              void* d_out, int out_size, void* d_ws, size_t ws_size,
                              hipStream_t stream) {
    const float* x     = (const float*)d_in[0];
    const int*   shift = (const int*)d_in[1];
    float*       out   = (float*)d_out;

    dim3 block(NTHR, 1, 1);
    dim3 grid(1024, 1, 1);     // one image per block; 4 blocks/CU exactly
    shift_aug_kernel<<<grid, block, 0, stream>>>(x, shift, out);
}

// Round 7
// 197.891 us; speedup vs baseline: 1.0549x; 1.0549x over previous
//
#include <hip/hip_runtime.h>

// RandomShiftsAug: out[n,c,h,w] = x[n,c, clamp(h+sy-4,0,83), clamp(w+sx-4,0,83)]
// N=1024, C=4, H=W=84, PAD=4, shift in [0,8] per (n, {x,y}).
// Reference's bilinear sample coords are exactly integer -> edge-clamped gather.
//
// R10 = EXACT REVERT to R4 (the inherited 195.5us kernel).
//   Session post-mortem: five structural theories tested and falsified --
//   (1) LDS bank conflicts (R5: conflict-free-ish variant slower; conflicts
//       were ~0.5 cyc/quad, negligible),
//   (2) read misalignment / VMEM count (R6: same ~70us),
//   (3) compiler-destroyed MLP (R7 sched_barrier defeated, VGPR stayed 24),
//   (4) latency / outstanding-bytes (R8: asm-forced 7-deep batch, VGPR 24->28
//       PROVES 7 quads live, 140KB/CU in flight -- dur unchanged 70.7us),
//   (5) launch-churn / persistence (R9: 1024-block grid-persistent loop, 73us).
//   Every deviation from R4 regressed (59 -> 68-74us). R4's shape -- aligned
//   copy-like block reads, LDS stage, one barrier, shifted LDS reads, aligned
//   stores, 28672 one-shot small blocks -- is the empirical optimum measured
//   on this op. Locking it in.

#define HW 84
#define WQ 21                 // 84/4 float4 per row
#define RPB 12                // rows per block; 84 = 7*12
#define PADV 4
#define PLANE (HW * HW)       // 7056 floats per (n,c) plane
#define IMG_ELEMS (4 * PLANE) // 28224 floats per image

__global__ __launch_bounds__(WQ * RPB)   // 252 threads
void shift_aug_kernel(const float* __restrict__ x,
                      const int* __restrict__ shift,
                      float* __restrict__ out) {
    __shared__ float lds[RPB][HW];

    const int tx = threadIdx.x;   // [0,21) : float4 index within row
    const int ty = threadIdx.y;   // [0,12) : row within band
    const int bx = blockIdx.x;    // [0,28) : (c, band)
    const int n  = blockIdx.y;    // [0,1024)

    const int c    = bx / 7;            // scalar
    const int band = (bx - c * 7) * RPB; // scalar

    // uniform address -> s_load_dwordx2; sx,sy live in SGPRs
    const int sx = shift[2 * n]     - PADV;
    const int sy = shift[2 * n + 1] - PADV;

    const int h  = band + ty;
    const int sh = min(max(h + sy, 0), HW - 1);   // clamped source row

    const float* __restrict__ plane = x + (size_t)n * IMG_ELEMS + (size_t)c * PLANE;

    // Stage source row sh: 21 lanes x 16B aligned, block reads ~4KB contiguous.
    float4 L = ((const float4*)(plane + sh * HW))[tx];
    ((float4*)&lds[ty][0])[tx] = L;
    __syncthreads();

    // Column shift + edge clamp out of LDS.
    const int wb = 4 * tx + sx;
    float4 v;
    v.x = lds[ty][min(max(wb + 0, 0), HW - 1)];
    v.y = lds[ty][min(max(wb + 1, 0), HW - 1)];
    v.z = lds[ty][min(max(wb + 2, 0), HW - 1)];
    v.w = lds[ty][min(max(wb + 3, 0), HW - 1)];

    float* __restrict__ oplane = out + (size_t)n * IMG_ELEMS + (size_t)c * PLANE;
    ((float4*)(oplane + h * HW))[tx] = v;
}

extern "C" void kernel_launch(void* const* d_in, const int* in_sizes, int n_in,
                              void* d_out, int out_size, void* d_ws, size_t ws_size,
                              hipStream_t stream) {
    const float* x     = (const float*)d_in[0];
    const int*   shift = (const int*)d_in[1];
    float*       out   = (float*)d_out;

    dim3 block(WQ, RPB, 1);        // 252 threads
    dim3 grid(28, 1024, 1);        // (c,band) x n
    shift_aug_kernel<<<grid, block, 0, stream>>>(x, shift, out);
}